// Round 2
// baseline (424.093 us; speedup 1.0000x reference)
//
#include <hip/hip_runtime.h>
#include <cstdint>

typedef float floatx4 __attribute__((ext_vector_type(4)));
typedef __bf16 bf16x8 __attribute__((ext_vector_type(8)));

__device__ __forceinline__ unsigned short f2b(float f) {
  union { float f; unsigned u; } v; v.f = f;
  return (unsigned short)((v.u + 0x7FFFu + ((v.u >> 16) & 1u)) >> 16);
}
__device__ __forceinline__ float b2f(unsigned short h) {
  union { unsigned u; float f; } v; v.u = ((unsigned)h) << 16;
  return v.f;
}

__device__ __forceinline__ void gload_lds16(const void* g, void* l) {
  __builtin_amdgcn_global_load_lds(
      (const __attribute__((address_space(1))) void*)g,
      (__attribute__((address_space(3))) void*)l, 16, 0, 0);
}

// ---------------- small prep kernels ----------------

__global__ void cast_bf16_kernel(const float* __restrict__ in,
                                 unsigned short* __restrict__ out, long n) {
  long i = (long)blockIdx.x * 256 + threadIdx.x;
  if (i < n) out[i] = f2b(in[i]);
}

// T[n][m] = w[n-m] for m<=n else 0;  N=2048, row-major 2048x2048 bf16
__global__ void build_T_kernel(const float* __restrict__ w,
                               unsigned short* __restrict__ T) {
  long i = (long)blockIdx.x * 256 + threadIdx.x;
  int n = (int)(i >> 11);
  int m = (int)(i & 2047);
  float v = (m <= n) ? w[n - m] : 0.0f;
  T[i] = f2b(v);
}

// x (B,2048,1024) f32 -> xT (B,1024,2048) bf16
__global__ void transpose_cast_kernel(const float* __restrict__ x,
                                      unsigned short* __restrict__ xT) {
  __shared__ float tile[32][33];
  int b = blockIdx.z;
  int n0 = blockIdx.y * 32;
  int d0 = blockIdx.x * 32;
  int tx = threadIdx.x;  // 0..31
  int ty = threadIdx.y;  // 0..7
  for (int i = ty; i < 32; i += 8)
    tile[i][tx] = x[((long)b * 2048 + n0 + i) * 1024 + d0 + tx];
  __syncthreads();
  for (int i = ty; i < 32; i += 8)
    xT[((long)b * 1024 + d0 + i) * 2048 + n0 + tx] = f2b(tile[tx][i]);
}

// ---------------- GEMM: C(MxN) = A(MxK) @ B(NxK)^T, bf16 in, f32 acc ----------------
// EPI 0: Cf = acc                              (plain, split-K partial)
// EPI 1: Cf = resid + scale[row]*acc           (conv epilogue)
// EPI 2: Cb = bf16(gelu(acc + bias[col]))      (MLP up)
// TRI:   lower-triangular A -> loop only kk < bm+128
template <int EPI, bool TRI>
__global__ __launch_bounds__(256, 2) void gemm_bt(
    const unsigned short* __restrict__ A, const unsigned short* __restrict__ B,
    int M, int N, int Kstride, int Kloop, long zsA, long zsB, long zsC,
    const float* __restrict__ resid, const float* __restrict__ scale,
    const float* __restrict__ bias,
    float* __restrict__ Cf, unsigned short* __restrict__ Cb) {
  __shared__ __align__(16) unsigned short As[128 * 32];
  __shared__ __align__(16) unsigned short Bs[128 * 32];
  const int tid = threadIdx.x;
  const int wid = tid >> 6;
  const int lane = tid & 63;
  const int quad = lane >> 4;
  const int l16 = lane & 15;
  const int wm = (wid >> 1) * 64;
  const int wn = (wid & 1) * 64;
  const long bm = (long)blockIdx.y * 128;
  const long bn = (long)blockIdx.x * 128;
  const int bz = blockIdx.z;
  const unsigned short* Ab = A + zsA * bz;
  const unsigned short* Bb = B + zsB * bz;

  floatx4 acc[4][4];
#pragma unroll
  for (int i = 0; i < 4; ++i)
#pragma unroll
    for (int j = 0; j < 4; ++j)
      acc[i][j] = floatx4{0.0f, 0.0f, 0.0f, 0.0f};

  // staging: 512 chunks of 16B per tile; chunk = pass*256 + tid
  // bank-conflict swizzle: LDS slot (row,kc) holds global chunk (row, kc^((row>>1)&3))
  const int sw = (tid >> 3) & 3;  // == ((row>>1)&3) for both passes
  const int r0 = tid >> 2, ks = ((tid & 3) ^ sw) * 8;
  const int r1 = 64 + r0;
  unsigned short* lA0 = As + (wid * 64) * 8;  // wave-uniform LDS bases
  unsigned short* lA1 = As + (256 + wid * 64) * 8;
  unsigned short* lB0 = Bs + (wid * 64) * 8;
  unsigned short* lB1 = Bs + (256 + wid * 64) * 8;
  const unsigned short* gA0 = Ab + (bm + r0) * (long)Kstride + ks;
  const unsigned short* gA1 = Ab + (bm + r1) * (long)Kstride + ks;
  const unsigned short* gB0 = Bb + (bn + r0) * (long)Kstride + ks;
  const unsigned short* gB1 = Bb + (bn + r1) * (long)Kstride + ks;

  const int kend = TRI ? min(Kloop, (int)bm + 128) : Kloop;
  for (int kk = 0; kk < kend; kk += 32) {
    __syncthreads();
    gload_lds16(gA0 + kk, lA0);
    gload_lds16(gA1 + kk, lA1);
    gload_lds16(gB0 + kk, lB0);
    gload_lds16(gB1 + kk, lB1);
    __syncthreads();
    bf16x8 af[4], bfr[4];
#pragma unroll
    for (int i = 0; i < 4; ++i) {
      const int ra = wm + i * 16 + l16;
      af[i] = *(const bf16x8*)(As + ra * 32 + (quad ^ ((ra >> 1) & 3)) * 8);
    }
#pragma unroll
    for (int j = 0; j < 4; ++j) {
      const int rb = wn + j * 16 + l16;
      bfr[j] = *(const bf16x8*)(Bs + rb * 32 + (quad ^ ((rb >> 1) & 3)) * 8);
    }
#pragma unroll
    for (int i = 0; i < 4; ++i)
#pragma unroll
      for (int j = 0; j < 4; ++j)
        acc[i][j] = __builtin_amdgcn_mfma_f32_16x16x32_bf16(af[i], bfr[j],
                                                            acc[i][j], 0, 0, 0);
  }

#pragma unroll
  for (int i = 0; i < 4; ++i) {
#pragma unroll
    for (int j = 0; j < 4; ++j) {
#pragma unroll
      for (int r = 0; r < 4; ++r) {
        long row = bm + wm + i * 16 + quad * 4 + r;
        long col = bn + wn + j * 16 + l16;
        long idx = (long)bz * zsC + row * (long)N + col;
        float v = acc[i][j][r];
        if (EPI == 0) {
          Cf[idx] = v;
        } else if (EPI == 1) {
          Cf[idx] = resid[idx] + scale[row] * v;
        } else {
          v += bias[col];
          v = 0.5f * v * (1.0f + erff(v * 0.70710678118654752f));
          Cb[idx] = f2b(v);
        }
      }
    }
  }
}

// ---------------- LayerNorm over D=1024, one block per row ----------------
__global__ __launch_bounds__(256) void ln_kernel(
    const float* __restrict__ in, const float* __restrict__ w,
    const float* __restrict__ b, float* __restrict__ outf,
    unsigned short* __restrict__ outb) {
  const long row = blockIdx.x;
  const int tid = threadIdx.x;
  float4 v = ((const float4*)in)[row * 256 + tid];
  float s = v.x + v.y + v.z + v.w;
  float ss = v.x * v.x + v.y * v.y + v.z * v.z + v.w * v.w;
#pragma unroll
  for (int off = 32; off > 0; off >>= 1) {
    s += __shfl_down(s, off);
    ss += __shfl_down(ss, off);
  }
  __shared__ float red[8];
  const int wid = tid >> 6, lane = tid & 63;
  if (lane == 0) { red[wid] = s; red[4 + wid] = ss; }
  __syncthreads();
  s = red[0] + red[1] + red[2] + red[3];
  ss = red[4] + red[5] + red[6] + red[7];
  const float mu = s * (1.0f / 1024.0f);
  const float var = ss * (1.0f / 1024.0f) - mu * mu;
  const float rs = rsqrtf(var + 1e-5f);
  float4 wv = ((const float4*)w)[tid];
  float4 bv = ((const float4*)b)[tid];
  float o0 = (v.x - mu) * rs * wv.x + bv.x;
  float o1 = (v.y - mu) * rs * wv.y + bv.y;
  float o2 = (v.z - mu) * rs * wv.z + bv.z;
  float o3 = (v.w - mu) * rs * wv.w + bv.w;
  if (outf) {
    float4 o{o0, o1, o2, o3};
    ((float4*)outf)[row * 256 + tid] = o;
  }
  if (outb) {
    ushort4 u{f2b(o0), f2b(o1), f2b(o2), f2b(o3)};
    ((ushort4*)outb)[row * 256 + tid] = u;
  }
}

// LN2 fused: v = x1 + scalar*(y0+y1+b2); out = LN(v)*w + b
__global__ __launch_bounds__(256) void ln2_fused_kernel(
    const float* __restrict__ y0, const float* __restrict__ y1,
    const unsigned short* __restrict__ x1b, const float* __restrict__ b2,
    const float* __restrict__ scalar_p, const float* __restrict__ w,
    const float* __restrict__ b, float* __restrict__ out) {
  const long row = blockIdx.x;
  const int tid = threadIdx.x;
  float4 a = ((const float4*)y0)[row * 256 + tid];
  float4 c = ((const float4*)y1)[row * 256 + tid];
  ushort4 xr = ((const ushort4*)x1b)[row * 256 + tid];
  float4 bias = ((const float4*)b2)[tid];
  const float scl = scalar_p[0];
  float4 v;
  v.x = b2f(xr.x) + scl * (a.x + c.x + bias.x);
  v.y = b2f(xr.y) + scl * (a.y + c.y + bias.y);
  v.z = b2f(xr.z) + scl * (a.z + c.z + bias.z);
  v.w = b2f(xr.w) + scl * (a.w + c.w + bias.w);
  float s = v.x + v.y + v.z + v.w;
  float ss = v.x * v.x + v.y * v.y + v.z * v.z + v.w * v.w;
#pragma unroll
  for (int off = 32; off > 0; off >>= 1) {
    s += __shfl_down(s, off);
    ss += __shfl_down(ss, off);
  }
  __shared__ float red[8];
  const int wid = tid >> 6, lane = tid & 63;
  if (lane == 0) { red[wid] = s; red[4 + wid] = ss; }
  __syncthreads();
  s = red[0] + red[1] + red[2] + red[3];
  ss = red[4] + red[5] + red[6] + red[7];
  const float mu = s * (1.0f / 1024.0f);
  const float var = ss * (1.0f / 1024.0f) - mu * mu;
  const float rs = rsqrtf(var + 1e-5f);
  float4 wv = ((const float4*)w)[tid];
  float4 bv = ((const float4*)b)[tid];
  float4 o;
  o.x = (v.x - mu) * rs * wv.x + bv.x;
  o.y = (v.y - mu) * rs * wv.y + bv.y;
  o.z = (v.z - mu) * rs * wv.z + bv.z;
  o.w = (v.w - mu) * rs * wv.w + bv.w;
  ((float4*)out)[row * 256 + tid] = o;
}

// ---------------- launch ----------------
extern "C" void kernel_launch(void* const* d_in, const int* in_sizes, int n_in,
                              void* d_out, int out_size, void* d_ws, size_t ws_size,
                              hipStream_t stream) {
  const float* x      = (const float*)d_in[0];
  const float* wconv  = (const float*)d_in[1];
  const float* scale  = (const float*)d_in[2];
  const float* ln1w   = (const float*)d_in[3];
  const float* ln1b   = (const float*)d_in[4];
  const float* W1     = (const float*)d_in[5];
  const float* b1     = (const float*)d_in[6];
  const float* W2     = (const float*)d_in[7];
  const float* b2     = (const float*)d_in[8];
  const float* scalar = (const float*)d_in[9];
  const float* ln2w   = (const float*)d_in[10];
  const float* ln2b   = (const float*)d_in[11];
  float* out = (float*)d_out;

  char* ws = (char*)d_ws;
  unsigned short* xT  = (unsigned short*)ws; ws += (size_t)4 * 1024 * 2048 * 2;  // 16 MB
  unsigned short* T   = (unsigned short*)ws; ws += (size_t)2048 * 2048 * 2;      //  8 MB
  unsigned short* W1b = (unsigned short*)ws; ws += (size_t)4096 * 1024 * 2;      //  8 MB
  unsigned short* W2b = (unsigned short*)ws; ws += (size_t)4096 * 1024 * 2;      //  8 MB
  float* y            = (float*)ws;          ws += (size_t)8192 * 1024 * 4;      // 32 MB (conv-out; later split-K partial 0)
  float* y1           = (float*)ws;          ws += (size_t)8192 * 1024 * 4;      // 32 MB (split-K partial 1, contiguous after y)
  unsigned short* x1b = (unsigned short*)ws; ws += (size_t)8192 * 1024 * 2;      // 16 MB
  unsigned short* h   = (unsigned short*)ws; ws += (size_t)8192 * 4096 * 2;      // 64 MB

  // prep: weight casts, Toeplitz build, x transpose+cast
  cast_bf16_kernel<<<16384, 256, 0, stream>>>(W1, W1b, (long)4096 * 1024);
  cast_bf16_kernel<<<16384, 256, 0, stream>>>(W2, W2b, (long)4096 * 1024);
  build_T_kernel<<<16384, 256, 0, stream>>>(wconv, T);
  transpose_cast_kernel<<<dim3(32, 64, 4), dim3(32, 8), 0, stream>>>(x, xT);

  // GEMM1: per batch, conv = T(2048x2048) @ xT_b(1024x2048)^T ; y = x + scale*conv
  // triangular skip: row-block bm needs only kk < bm+128
  gemm_bt<1, true><<<dim3(8, 16, 4), 256, 0, stream>>>(
      T, xT, 2048, 1024, 2048, 2048, 0L, (long)1024 * 2048, (long)2048 * 1024,
      x, scale, nullptr, y, nullptr);
  // LN1 -> x1 (bf16 only)
  ln_kernel<<<8192, 256, 0, stream>>>(y, ln1w, ln1b, nullptr, x1b);
  // GEMM2: h = gelu(x1(8192x1024) @ W1(4096x1024)^T + b1) -> bf16
  gemm_bt<2, false><<<dim3(32, 64, 1), 256, 0, stream>>>(
      x1b, W1b, 8192, 4096, 1024, 1024, 0L, 0L, 0L,
      nullptr, nullptr, b1, nullptr, h);
  // GEMM3 split-K=2: y/y1 = partial h(8192x4096) @ W2(1024x4096)^T
  gemm_bt<0, false><<<dim3(8, 64, 2), 256, 0, stream>>>(
      h, W2b, 8192, 1024, 4096, 2048, 2048L, 2048L, (long)8192 * 1024,
      nullptr, nullptr, nullptr, y, nullptr);
  // LN2 fused: out = LN(x1 + scalar*(y0+y1+b2))
  ln2_fused_kernel<<<8192, 256, 0, stream>>>(y, y1, x1b, b2, scalar, ln2w, ln2b, out);
}

// Round 3
// 395.022 us; speedup vs baseline: 1.0736x; 1.0736x over previous
//
#include <hip/hip_runtime.h>
#include <cstdint>

typedef float floatx4 __attribute__((ext_vector_type(4)));
typedef __bf16 bf16x8 __attribute__((ext_vector_type(8)));

__device__ __forceinline__ unsigned short f2b(float f) {
  union { float f; unsigned u; } v; v.f = f;
  return (unsigned short)((v.u + 0x7FFFu + ((v.u >> 16) & 1u)) >> 16);
}
__device__ __forceinline__ float b2f(unsigned short h) {
  union { unsigned u; float f; } v; v.u = ((unsigned)h) << 16;
  return v.f;
}

__device__ __forceinline__ void gload_lds16(const void* g, void* l) {
  __builtin_amdgcn_global_load_lds(
      (const __attribute__((address_space(1))) void*)g,
      (__attribute__((address_space(3))) void*)l, 16, 0, 0);
}

// ---------------- small prep kernels ----------------

__global__ void cast_bf16_kernel(const float* __restrict__ in,
                                 unsigned short* __restrict__ out, long n) {
  long i = (long)blockIdx.x * 256 + threadIdx.x;
  if (i < n) out[i] = f2b(in[i]);
}

// T[n][m] = w[n-m] for m<=n else 0;  N=2048, row-major 2048x2048 bf16
__global__ void build_T_kernel(const float* __restrict__ w,
                               unsigned short* __restrict__ T) {
  long i = (long)blockIdx.x * 256 + threadIdx.x;
  int n = (int)(i >> 11);
  int m = (int)(i & 2047);
  float v = (m <= n) ? w[n - m] : 0.0f;
  T[i] = f2b(v);
}

// x (B,2048,1024) f32 -> xT (B,1024,2048) bf16
__global__ void transpose_cast_kernel(const float* __restrict__ x,
                                      unsigned short* __restrict__ xT) {
  __shared__ float tile[32][33];
  int b = blockIdx.z;
  int n0 = blockIdx.y * 32;
  int d0 = blockIdx.x * 32;
  int tx = threadIdx.x;  // 0..31
  int ty = threadIdx.y;  // 0..7
  for (int i = ty; i < 32; i += 8)
    tile[i][tx] = x[((long)b * 2048 + n0 + i) * 1024 + d0 + tx];
  __syncthreads();
  for (int i = ty; i < 32; i += 8)
    xT[((long)b * 1024 + d0 + i) * 2048 + n0 + tx] = f2b(tile[tx][i]);
}

// ---------------- GEMM: C(MxN) = A(MxK) @ B(NxK)^T, bf16 in, f32 acc ----------------
// 1-D grid.x with explicit XCD-rectangle swizzle (xcd = bid&7 round-robin heuristic):
//   non-TRI: per-XCD rectangle rx cols x ryb rows of 128-blocks; XCDs tiled gxn wide.
//   TRI (lower-triangular A): rx cols x 2 rows, rows {xcd, 15-xcd} for load balance.
// EPI 0: Cf = acc                              (plain, split-K partial)
// EPI 1: Cf = resid + scale[row]*acc           (conv epilogue)
// EPI 2: Cb = bf16(gelu(acc + bias[col]))      (MLP up)
template <int EPI, bool TRI>
__global__ __launch_bounds__(256, 4) void gemm_bt(
    const unsigned short* __restrict__ A, const unsigned short* __restrict__ B,
    int N, int Kstride, int Kloop, long zsA, long zsB, long zsC,
    int rx, int ryb, int gxn,
    const float* __restrict__ resid, const float* __restrict__ scale,
    const float* __restrict__ bias,
    float* __restrict__ Cf, unsigned short* __restrict__ Cb) {
  __shared__ __align__(16) unsigned short As[128 * 32];
  __shared__ __align__(16) unsigned short Bs[128 * 32];
  const int tid = threadIdx.x;
  const int wid = tid >> 6;
  const int lane = tid & 63;
  const int quad = lane >> 4;
  const int l16 = lane & 15;
  const int wm = (wid >> 1) * 64;
  const int wn = (wid & 1) * 64;

  // XCD-rectangle block swizzle
  const int bid = blockIdx.x;
  const int xcd = bid & 7;
  const int ib = bid >> 3;
  const int ci = ib % rx;
  const int ri = ib / rx;
  long bm, bn;
  if (TRI) {
    bm = (long)(ri == 0 ? xcd : 15 - xcd) * 128;
    bn = (long)ci * 128;
  } else {
    const int gx = xcd % gxn;
    const int gy = xcd / gxn;
    bm = (long)(gy * ryb + ri) * 128;
    bn = (long)(gx * rx + ci) * 128;
  }
  const int bz = blockIdx.z;
  const unsigned short* Ab = A + zsA * bz;
  const unsigned short* Bb = B + zsB * bz;

  floatx4 acc[4][4];
#pragma unroll
  for (int i = 0; i < 4; ++i)
#pragma unroll
    for (int j = 0; j < 4; ++j)
      acc[i][j] = floatx4{0.0f, 0.0f, 0.0f, 0.0f};

  // staging: 512 chunks of 16B per tile; chunk = pass*256 + tid
  // bank-conflict swizzle: LDS slot (row,kc) holds global chunk (row, kc^((row>>1)&3))
  const int sw = (tid >> 3) & 3;  // == ((row>>1)&3) for both passes
  const int r0 = tid >> 2, ks = ((tid & 3) ^ sw) * 8;
  const int r1 = 64 + r0;
  unsigned short* lA0 = As + (wid * 64) * 8;  // wave-uniform LDS bases
  unsigned short* lA1 = As + (256 + wid * 64) * 8;
  unsigned short* lB0 = Bs + (wid * 64) * 8;
  unsigned short* lB1 = Bs + (256 + wid * 64) * 8;
  const unsigned short* gA0 = Ab + (bm + r0) * (long)Kstride + ks;
  const unsigned short* gA1 = Ab + (bm + r1) * (long)Kstride + ks;
  const unsigned short* gB0 = Bb + (bn + r0) * (long)Kstride + ks;
  const unsigned short* gB1 = Bb + (bn + r1) * (long)Kstride + ks;

  const int kend = TRI ? min(Kloop, (int)bm + 128) : Kloop;
  for (int kk = 0; kk < kend; kk += 32) {
    __syncthreads();
    gload_lds16(gA0 + kk, lA0);
    gload_lds16(gA1 + kk, lA1);
    gload_lds16(gB0 + kk, lB0);
    gload_lds16(gB1 + kk, lB1);
    __syncthreads();
    bf16x8 af[4], bfr[4];
#pragma unroll
    for (int i = 0; i < 4; ++i) {
      const int ra = wm + i * 16 + l16;
      af[i] = *(const bf16x8*)(As + ra * 32 + (quad ^ ((ra >> 1) & 3)) * 8);
    }
#pragma unroll
    for (int j = 0; j < 4; ++j) {
      const int rb = wn + j * 16 + l16;
      bfr[j] = *(const bf16x8*)(Bs + rb * 32 + (quad ^ ((rb >> 1) & 3)) * 8);
    }
#pragma unroll
    for (int i = 0; i < 4; ++i)
#pragma unroll
      for (int j = 0; j < 4; ++j)
        acc[i][j] = __builtin_amdgcn_mfma_f32_16x16x32_bf16(af[i], bfr[j],
                                                            acc[i][j], 0, 0, 0);
  }

#pragma unroll
  for (int i = 0; i < 4; ++i) {
#pragma unroll
    for (int j = 0; j < 4; ++j) {
#pragma unroll
      for (int r = 0; r < 4; ++r) {
        long row = bm + wm + i * 16 + quad * 4 + r;
        long col = bn + wn + j * 16 + l16;
        long idx = (long)bz * zsC + row * (long)N + col;
        float v = acc[i][j][r];
        if (EPI == 0) {
          Cf[idx] = v;
        } else if (EPI == 1) {
          Cf[idx] = resid[idx] + scale[row] * v;
        } else {
          v += bias[col];
          v = 0.5f * v * (1.0f + erff(v * 0.70710678118654752f));
          Cb[idx] = f2b(v);
        }
      }
    }
  }
}

// ---------------- LayerNorm over D=1024, one block per row ----------------
__global__ __launch_bounds__(256) void ln_kernel(
    const float* __restrict__ in, const float* __restrict__ w,
    const float* __restrict__ b, float* __restrict__ outf,
    unsigned short* __restrict__ outb) {
  const long row = blockIdx.x;
  const int tid = threadIdx.x;
  float4 v = ((const float4*)in)[row * 256 + tid];
  float s = v.x + v.y + v.z + v.w;
  float ss = v.x * v.x + v.y * v.y + v.z * v.z + v.w * v.w;
#pragma unroll
  for (int off = 32; off > 0; off >>= 1) {
    s += __shfl_down(s, off);
    ss += __shfl_down(ss, off);
  }
  __shared__ float red[8];
  const int wid = tid >> 6, lane = tid & 63;
  if (lane == 0) { red[wid] = s; red[4 + wid] = ss; }
  __syncthreads();
  s = red[0] + red[1] + red[2] + red[3];
  ss = red[4] + red[5] + red[6] + red[7];
  const float mu = s * (1.0f / 1024.0f);
  const float var = ss * (1.0f / 1024.0f) - mu * mu;
  const float rs = rsqrtf(var + 1e-5f);
  float4 wv = ((const float4*)w)[tid];
  float4 bv = ((const float4*)b)[tid];
  float o0 = (v.x - mu) * rs * wv.x + bv.x;
  float o1 = (v.y - mu) * rs * wv.y + bv.y;
  float o2 = (v.z - mu) * rs * wv.z + bv.z;
  float o3 = (v.w - mu) * rs * wv.w + bv.w;
  if (outf) {
    float4 o{o0, o1, o2, o3};
    ((float4*)outf)[row * 256 + tid] = o;
  }
  if (outb) {
    ushort4 u{f2b(o0), f2b(o1), f2b(o2), f2b(o3)};
    ((ushort4*)outb)[row * 256 + tid] = u;
  }
}

// LN2 fused: v = x1 + scalar*(y0+y1+b2); out = LN(v)*w + b
__global__ __launch_bounds__(256) void ln2_fused_kernel(
    const float* __restrict__ y0, const float* __restrict__ y1,
    const unsigned short* __restrict__ x1b, const float* __restrict__ b2,
    const float* __restrict__ scalar_p, const float* __restrict__ w,
    const float* __restrict__ b, float* __restrict__ out) {
  const long row = blockIdx.x;
  const int tid = threadIdx.x;
  float4 a = ((const float4*)y0)[row * 256 + tid];
  float4 c = ((const float4*)y1)[row * 256 + tid];
  ushort4 xr = ((const ushort4*)x1b)[row * 256 + tid];
  float4 bias = ((const float4*)b2)[tid];
  const float scl = scalar_p[0];
  float4 v;
  v.x = b2f(xr.x) + scl * (a.x + c.x + bias.x);
  v.y = b2f(xr.y) + scl * (a.y + c.y + bias.y);
  v.z = b2f(xr.z) + scl * (a.z + c.z + bias.z);
  v.w = b2f(xr.w) + scl * (a.w + c.w + bias.w);
  float s = v.x + v.y + v.z + v.w;
  float ss = v.x * v.x + v.y * v.y + v.z * v.z + v.w * v.w;
#pragma unroll
  for (int off = 32; off > 0; off >>= 1) {
    s += __shfl_down(s, off);
    ss += __shfl_down(ss, off);
  }
  __shared__ float red[8];
  const int wid = tid >> 6, lane = tid & 63;
  if (lane == 0) { red[wid] = s; red[4 + wid] = ss; }
  __syncthreads();
  s = red[0] + red[1] + red[2] + red[3];
  ss = red[4] + red[5] + red[6] + red[7];
  const float mu = s * (1.0f / 1024.0f);
  const float var = ss * (1.0f / 1024.0f) - mu * mu;
  const float rs = rsqrtf(var + 1e-5f);
  float4 wv = ((const float4*)w)[tid];
  float4 bv = ((const float4*)b)[tid];
  float4 o;
  o.x = (v.x - mu) * rs * wv.x + bv.x;
  o.y = (v.y - mu) * rs * wv.y + bv.y;
  o.z = (v.z - mu) * rs * wv.z + bv.z;
  o.w = (v.w - mu) * rs * wv.w + bv.w;
  ((float4*)out)[row * 256 + tid] = o;
}

// ---------------- launch ----------------
extern "C" void kernel_launch(void* const* d_in, const int* in_sizes, int n_in,
                              void* d_out, int out_size, void* d_ws, size_t ws_size,
                              hipStream_t stream) {
  const float* x      = (const float*)d_in[0];
  const float* wconv  = (const float*)d_in[1];
  const float* scale  = (const float*)d_in[2];
  const float* ln1w   = (const float*)d_in[3];
  const float* ln1b   = (const float*)d_in[4];
  const float* W1     = (const float*)d_in[5];
  const float* b1     = (const float*)d_in[6];
  const float* W2     = (const float*)d_in[7];
  const float* b2     = (const float*)d_in[8];
  const float* scalar = (const float*)d_in[9];
  const float* ln2w   = (const float*)d_in[10];
  const float* ln2b   = (const float*)d_in[11];
  float* out = (float*)d_out;

  char* ws = (char*)d_ws;
  unsigned short* xT  = (unsigned short*)ws; ws += (size_t)4 * 1024 * 2048 * 2;  // 16 MB
  unsigned short* T   = (unsigned short*)ws; ws += (size_t)2048 * 2048 * 2;      //  8 MB
  unsigned short* W1b = (unsigned short*)ws; ws += (size_t)4096 * 1024 * 2;      //  8 MB
  unsigned short* W2b = (unsigned short*)ws; ws += (size_t)4096 * 1024 * 2;      //  8 MB
  float* y            = (float*)ws;          ws += (size_t)8192 * 1024 * 4;      // 32 MB (conv-out; later split-K partial 0)
  float* y1           = (float*)ws;          ws += (size_t)8192 * 1024 * 4;      // 32 MB (split-K partial 1)
  unsigned short* x1b = (unsigned short*)ws; ws += (size_t)8192 * 1024 * 2;      // 16 MB
  unsigned short* h   = (unsigned short*)ws; ws += (size_t)8192 * 4096 * 2;      // 64 MB

  // prep: weight casts, Toeplitz build, x transpose+cast
  cast_bf16_kernel<<<16384, 256, 0, stream>>>(W1, W1b, (long)4096 * 1024);
  cast_bf16_kernel<<<16384, 256, 0, stream>>>(W2, W2b, (long)4096 * 1024);
  build_T_kernel<<<16384, 256, 0, stream>>>(wconv, T);
  transpose_cast_kernel<<<dim3(32, 64, 4), dim3(32, 8), 0, stream>>>(x, xT);

  // GEMM1: per batch, conv = T(2048x2048) @ xT_b(1024x2048)^T ; y = x + scale*conv
  // TRI swizzle: rows {xcd,15-xcd} per XCD, 8 col-blocks each -> balanced + T-band L2-resident
  gemm_bt<1, true><<<dim3(128, 1, 4), 256, 0, stream>>>(
      T, xT, 1024, 2048, 2048, 0L, (long)1024 * 2048, (long)2048 * 1024,
      8, 2, 1, x, scale, nullptr, y, nullptr);
  // LN1 -> x1 (bf16 only)
  ln_kernel<<<8192, 256, 0, stream>>>(y, ln1w, ln1b, nullptr, x1b);
  // GEMM2: h = gelu(x1(8192x1024) @ W1(4096x1024)^T + b1) -> bf16
  // 64x32 blocks; per-XCD rect 16x16, XCD grid 2 wide x 4 tall
  gemm_bt<2, false><<<dim3(2048, 1, 1), 256, 0, stream>>>(
      x1b, W1b, 4096, 1024, 1024, 0L, 0L, 0L,
      16, 16, 2, nullptr, nullptr, b1, nullptr, h);
  // GEMM3 split-K=2: y/y1 = partial h(8192x4096) @ W2(1024x4096)^T
  // per z: 64x8 blocks; per-XCD rect 8x8, XCDs stacked vertically
  gemm_bt<0, false><<<dim3(512, 1, 2), 256, 0, stream>>>(
      h, W2b, 1024, 4096, 2048, 2048L, 2048L, (long)8192 * 1024,
      8, 8, 1, nullptr, nullptr, nullptr, y, nullptr);
  // LN2 fused: out = LN(x1 + scalar*(y0+y1+b2))
  ln2_fused_kernel<<<8192, 256, 0, stream>>>(y, y1, x1b, b2, scalar, ln2w, ln2b, out);
}

// Round 4
// 312.233 us; speedup vs baseline: 1.3583x; 1.2652x over previous
//
#include <hip/hip_runtime.h>
#include <cstdint>

typedef float floatx4 __attribute__((ext_vector_type(4)));
typedef __bf16 bf16x8 __attribute__((ext_vector_type(8)));
typedef int intx8 __attribute__((ext_vector_type(8)));

__device__ __forceinline__ unsigned short f2b(float f) {
  union { float f; unsigned u; } v; v.f = f;
  return (unsigned short)((v.u + 0x7FFFu + ((v.u >> 16) & 1u)) >> 16);
}
__device__ __forceinline__ float b2f(unsigned short h) {
  union { unsigned u; float f; } v; v.u = ((unsigned)h) << 16;
  return v.f;
}

__device__ __forceinline__ void gload_lds16(const void* g, void* l) {
  __builtin_amdgcn_global_load_lds(
      (const __attribute__((address_space(1))) void*)g,
      (__attribute__((address_space(3))) void*)l, 16, 0, 0);
}

// ---------------- small prep kernels ----------------

// W (f32) -> fp8 e4m3 of (W * 64); consumed with MX block-scale 2^-6
__global__ void cast_f8x64_kernel(const float* __restrict__ in,
                                  int* __restrict__ out) {
  long i = (long)blockIdx.x * 256 + threadIdx.x;
  float4 v = ((const float4*)in)[i];
  int pk = __builtin_amdgcn_cvt_pk_fp8_f32(v.x * 64.0f, v.y * 64.0f, 0, false);
  pk = __builtin_amdgcn_cvt_pk_fp8_f32(v.z * 64.0f, v.w * 64.0f, pk, true);
  out[i] = pk;
}

// T[n][m] = w[n-m] for m<=n else 0;  N=2048, row-major 2048x2048 bf16
__global__ void build_T_kernel(const float* __restrict__ w,
                               unsigned short* __restrict__ T) {
  long i = (long)blockIdx.x * 256 + threadIdx.x;
  int n = (int)(i >> 11);
  int m = (int)(i & 2047);
  float v = (m <= n) ? w[n - m] : 0.0f;
  T[i] = f2b(v);
}

// x (B,2048,1024) f32 -> xT (B,1024,2048) bf16
__global__ void transpose_cast_kernel(const float* __restrict__ x,
                                      unsigned short* __restrict__ xT) {
  __shared__ float tile[32][33];
  int b = blockIdx.z;
  int n0 = blockIdx.y * 32;
  int d0 = blockIdx.x * 32;
  int tx = threadIdx.x;  // 0..31
  int ty = threadIdx.y;  // 0..7
  for (int i = ty; i < 32; i += 8)
    tile[i][tx] = x[((long)b * 2048 + n0 + i) * 1024 + d0 + tx];
  __syncthreads();
  for (int i = ty; i < 32; i += 8)
    xT[((long)b * 1024 + d0 + i) * 2048 + n0 + tx] = f2b(tile[tx][i]);
}

// ---------------- bf16 GEMM (GEMM1 only): C = A @ B^T, triangular ----------------
// EPI 1: Cf = resid + scale[row]*acc
__global__ __launch_bounds__(256, 4) void gemm_bt(
    const unsigned short* __restrict__ A, const unsigned short* __restrict__ B,
    int N, int Kstride, int Kloop, long zsA, long zsB, long zsC,
    int rx,
    const float* __restrict__ resid, const float* __restrict__ scale,
    float* __restrict__ Cf) {
  __shared__ __align__(16) unsigned short As[128 * 32];
  __shared__ __align__(16) unsigned short Bs[128 * 32];
  const int tid = threadIdx.x;
  const int wid = tid >> 6;
  const int lane = tid & 63;
  const int quad = lane >> 4;
  const int l16 = lane & 15;
  const int wm = (wid >> 1) * 64;
  const int wn = (wid & 1) * 64;

  // TRI swizzle: rows {xcd, 15-xcd} per XCD for triangular load balance
  const int bid = blockIdx.x;
  const int xcd = bid & 7;
  const int ib = bid >> 3;
  const int ci = ib % rx;
  const int ri = ib / rx;
  const long bm = (long)(ri == 0 ? xcd : 15 - xcd) * 128;
  const long bn = (long)ci * 128;
  const int bz = blockIdx.z;
  const unsigned short* Ab = A + zsA * bz;
  const unsigned short* Bb = B + zsB * bz;

  floatx4 acc[4][4];
#pragma unroll
  for (int i = 0; i < 4; ++i)
#pragma unroll
    for (int j = 0; j < 4; ++j)
      acc[i][j] = floatx4{0.0f, 0.0f, 0.0f, 0.0f};

  const int sw = (tid >> 3) & 3;
  const int r0 = tid >> 2, ks = ((tid & 3) ^ sw) * 8;
  const int r1 = 64 + r0;
  unsigned short* lA0 = As + (wid * 64) * 8;
  unsigned short* lA1 = As + (256 + wid * 64) * 8;
  unsigned short* lB0 = Bs + (wid * 64) * 8;
  unsigned short* lB1 = Bs + (256 + wid * 64) * 8;
  const unsigned short* gA0 = Ab + (bm + r0) * (long)Kstride + ks;
  const unsigned short* gA1 = Ab + (bm + r1) * (long)Kstride + ks;
  const unsigned short* gB0 = Bb + (bn + r0) * (long)Kstride + ks;
  const unsigned short* gB1 = Bb + (bn + r1) * (long)Kstride + ks;

  const int kend = min(Kloop, (int)bm + 128);
  for (int kk = 0; kk < kend; kk += 32) {
    __syncthreads();
    gload_lds16(gA0 + kk, lA0);
    gload_lds16(gA1 + kk, lA1);
    gload_lds16(gB0 + kk, lB0);
    gload_lds16(gB1 + kk, lB1);
    __syncthreads();
    bf16x8 af[4], bfr[4];
#pragma unroll
    for (int i = 0; i < 4; ++i) {
      const int ra = wm + i * 16 + l16;
      af[i] = *(const bf16x8*)(As + ra * 32 + (quad ^ ((ra >> 1) & 3)) * 8);
    }
#pragma unroll
    for (int j = 0; j < 4; ++j) {
      const int rb = wn + j * 16 + l16;
      bfr[j] = *(const bf16x8*)(Bs + rb * 32 + (quad ^ ((rb >> 1) & 3)) * 8);
    }
#pragma unroll
    for (int i = 0; i < 4; ++i)
#pragma unroll
      for (int j = 0; j < 4; ++j)
        acc[i][j] = __builtin_amdgcn_mfma_f32_16x16x32_bf16(af[i], bfr[j],
                                                            acc[i][j], 0, 0, 0);
  }

#pragma unroll
  for (int i = 0; i < 4; ++i)
#pragma unroll
    for (int j = 0; j < 4; ++j)
#pragma unroll
      for (int r = 0; r < 4; ++r) {
        long row = bm + wm + i * 16 + quad * 4 + r;
        long col = bn + wn + j * 16 + l16;
        long idx = (long)bz * zsC + row * (long)N + col;
        Cf[idx] = resid[idx] + scale[row] * acc[i][j][r];
      }
}

// ---------------- fp8 GEMM (MX-scaled, trivial scales): C = A @ B^T ----------------
// A fp8 e4m3 (scale 1.0), B fp8 e4m3 pre-scaled x64 (block-scale 2^-6).
// BM=BN=BK=128. mfma_scale_f32_16x16x128_f8f6f4. C/D layout same as 16x16 bf16.
// EPI 0: Cf = acc                         (split-K partial)
// EPI 2: C8 = fp8(gelu_tanh(acc+bias))    (MLP up, h output)
template <int EPI>
__global__ __launch_bounds__(256, 4) void gemm_f8(
    const unsigned char* __restrict__ A, const unsigned char* __restrict__ B,
    int N, int Kstride, int Kloop, long zsA, long zsB, long zsC,
    int rx, int ryb, int gxn,
    const float* __restrict__ bias,
    float* __restrict__ Cf, unsigned char* __restrict__ C8) {
  __shared__ __align__(16) unsigned char As[128 * 128];
  __shared__ __align__(16) unsigned char Bs[128 * 128];
  const int tid = threadIdx.x;
  const int wid = tid >> 6;
  const int lane = tid & 63;
  const int quad = lane >> 4;
  const int l16 = lane & 15;
  const int wm = (wid >> 1) * 64;
  const int wn = (wid & 1) * 64;

  const int bid = blockIdx.x;
  const int xcd = bid & 7;
  const int ib = bid >> 3;
  const int ci = ib % rx;
  const int ri = ib / rx;
  const int gx = xcd % gxn;
  const int gy = xcd / gxn;
  const long bm = (long)(gy * ryb + ri) * 128;
  const long bn = (long)(gx * rx + ci) * 128;
  const int bz = blockIdx.z;
  const unsigned char* Ab = A + zsA * bz;
  const unsigned char* Bb = B + zsB * bz;

  floatx4 acc[4][4];
#pragma unroll
  for (int i = 0; i < 4; ++i)
#pragma unroll
    for (int j = 0; j < 4; ++j)
      acc[i][j] = floatx4{0.0f, 0.0f, 0.0f, 0.0f};

  // staging: tile = 128 rows x 128 B = 1024 chunks of 16B; 4 passes of 256 thr.
  // LDS slot s: row = s>>3, c = s&7. Slot holds global chunk with 32B-pair
  // index XOR-swizzled by row&3 (bit0 of chunk kept -> 16B halves stay ordered).
  const unsigned char* gA[4];
  const unsigned char* gB[4];
  unsigned char* lA[4];
  unsigned char* lB[4];
#pragma unroll
  for (int p = 0; p < 4; ++p) {
    const int s = p * 256 + tid;
    const int row = s >> 3;
    const int c = s & 7;
    const int gc = ((((c >> 1) ^ (row & 3)) << 1) | (c & 1));
    gA[p] = Ab + (bm + row) * (long)Kstride + gc * 16;
    gB[p] = Bb + (bn + row) * (long)Kstride + gc * 16;
    lA[p] = As + p * 4096 + wid * 1024;  // wave-uniform base + lane*16 implicit
    lB[p] = Bs + p * 4096 + wid * 1024;
  }

  for (int kk = 0; kk < Kloop; kk += 128) {
    __syncthreads();
#pragma unroll
    for (int p = 0; p < 4; ++p) {
      gload_lds16(gA[p] + kk, lA[p]);
      gload_lds16(gB[p] + kk, lB[p]);
    }
    __syncthreads();
    intx8 af[4], bfr[4];
#pragma unroll
    for (int i = 0; i < 4; ++i) {
      const int ra = wm + i * 16 + l16;
      const int off = ra * 128 + (quad ^ (ra & 3)) * 32;
      union { intx8 v; int4 q[2]; } u;
      u.q[0] = *(const int4*)(As + off);
      u.q[1] = *(const int4*)(As + off + 16);
      af[i] = u.v;
    }
#pragma unroll
    for (int j = 0; j < 4; ++j) {
      const int rb = wn + j * 16 + l16;
      const int off = rb * 128 + (quad ^ (rb & 3)) * 32;
      union { intx8 v; int4 q[2]; } u;
      u.q[0] = *(const int4*)(Bs + off);
      u.q[1] = *(const int4*)(Bs + off + 16);
      bfr[j] = u.v;
    }
#pragma unroll
    for (int i = 0; i < 4; ++i)
#pragma unroll
      for (int j = 0; j < 4; ++j)
        acc[i][j] = __builtin_amdgcn_mfma_scale_f32_16x16x128_f8f6f4(
            af[i], bfr[j], acc[i][j], 0 /*fp8*/, 0 /*fp8*/,
            0, 0x7F7F7F7F /*A scale 2^0*/, 0, 0x79797979 /*B scale 2^-6*/);
  }

#pragma unroll
  for (int i = 0; i < 4; ++i)
#pragma unroll
    for (int j = 0; j < 4; ++j)
#pragma unroll
      for (int r = 0; r < 4; ++r) {
        long row = bm + wm + i * 16 + quad * 4 + r;
        long col = bn + wn + j * 16 + l16;
        long idx = (long)bz * zsC + row * (long)N + col;
        float v = acc[i][j][r];
        if (EPI == 0) {
          Cf[idx] = v;
        } else {
          v += bias[col];
          // tanh-form gelu: u = sqrt(2/pi)*(v+0.044715 v^3); gelu = v*t/(t+1)
          float u = v * (0.7978845608f + 0.0356774081f * v * v);
          float t = exp2f(u * 2.885390082f);  // exp(2u)
          float g = v * t / (t + 1.0f);
          int pk = __builtin_amdgcn_cvt_pk_fp8_f32(g, 0.0f, 0, false);
          C8[idx] = (unsigned char)(pk & 0xFF);
        }
      }
}

// ---------------- LayerNorm over D=1024, one block per row ----------------
// outputs bf16 (LN2 residual) + fp8 (GEMM2 A operand)
__global__ __launch_bounds__(256) void ln_kernel(
    const float* __restrict__ in, const float* __restrict__ w,
    const float* __restrict__ b, unsigned short* __restrict__ outb,
    int* __restrict__ outf8) {
  const long row = blockIdx.x;
  const int tid = threadIdx.x;
  float4 v = ((const float4*)in)[row * 256 + tid];
  float s = v.x + v.y + v.z + v.w;
  float ss = v.x * v.x + v.y * v.y + v.z * v.z + v.w * v.w;
#pragma unroll
  for (int off = 32; off > 0; off >>= 1) {
    s += __shfl_down(s, off);
    ss += __shfl_down(ss, off);
  }
  __shared__ float red[8];
  const int wid = tid >> 6, lane = tid & 63;
  if (lane == 0) { red[wid] = s; red[4 + wid] = ss; }
  __syncthreads();
  s = red[0] + red[1] + red[2] + red[3];
  ss = red[4] + red[5] + red[6] + red[7];
  const float mu = s * (1.0f / 1024.0f);
  const float var = ss * (1.0f / 1024.0f) - mu * mu;
  const float rs = rsqrtf(var + 1e-5f);
  float4 wv = ((const float4*)w)[tid];
  float4 bv = ((const float4*)b)[tid];
  float o0 = (v.x - mu) * rs * wv.x + bv.x;
  float o1 = (v.y - mu) * rs * wv.y + bv.y;
  float o2 = (v.z - mu) * rs * wv.z + bv.z;
  float o3 = (v.w - mu) * rs * wv.w + bv.w;
  ushort4 u{f2b(o0), f2b(o1), f2b(o2), f2b(o3)};
  ((ushort4*)outb)[row * 256 + tid] = u;
  int pk = __builtin_amdgcn_cvt_pk_fp8_f32(o0, o1, 0, false);
  pk = __builtin_amdgcn_cvt_pk_fp8_f32(o2, o3, pk, true);
  outf8[row * 256 + tid] = pk;
}

// LN2 fused: v = x1 + scalar*(y0+y1+b2); out = LN(v)*w + b
__global__ __launch_bounds__(256) void ln2_fused_kernel(
    const float* __restrict__ y0, const float* __restrict__ y1,
    const unsigned short* __restrict__ x1b, const float* __restrict__ b2,
    const float* __restrict__ scalar_p, const float* __restrict__ w,
    const float* __restrict__ b, float* __restrict__ out) {
  const long row = blockIdx.x;
  const int tid = threadIdx.x;
  float4 a = ((const float4*)y0)[row * 256 + tid];
  float4 c = ((const float4*)y1)[row * 256 + tid];
  ushort4 xr = ((const ushort4*)x1b)[row * 256 + tid];
  float4 bias = ((const float4*)b2)[tid];
  const float scl = scalar_p[0];
  float4 v;
  v.x = b2f(xr.x) + scl * (a.x + c.x + bias.x);
  v.y = b2f(xr.y) + scl * (a.y + c.y + bias.y);
  v.z = b2f(xr.z) + scl * (a.z + c.z + bias.z);
  v.w = b2f(xr.w) + scl * (a.w + c.w + bias.w);
  float s = v.x + v.y + v.z + v.w;
  float ss = v.x * v.x + v.y * v.y + v.z * v.z + v.w * v.w;
#pragma unroll
  for (int off = 32; off > 0; off >>= 1) {
    s += __shfl_down(s, off);
    ss += __shfl_down(ss, off);
  }
  __shared__ float red[8];
  const int wid = tid >> 6, lane = tid & 63;
  if (lane == 0) { red[wid] = s; red[4 + wid] = ss; }
  __syncthreads();
  s = red[0] + red[1] + red[2] + red[3];
  ss = red[4] + red[5] + red[6] + red[7];
  const float mu = s * (1.0f / 1024.0f);
  const float var = ss * (1.0f / 1024.0f) - mu * mu;
  const float rs = rsqrtf(var + 1e-5f);
  float4 wv = ((const float4*)w)[tid];
  float4 bv = ((const float4*)b)[tid];
  float4 o;
  o.x = (v.x - mu) * rs * wv.x + bv.x;
  o.y = (v.y - mu) * rs * wv.y + bv.y;
  o.z = (v.z - mu) * rs * wv.z + bv.z;
  o.w = (v.w - mu) * rs * wv.w + bv.w;
  ((float4*)out)[row * 256 + tid] = o;
}

// ---------------- launch ----------------
extern "C" void kernel_launch(void* const* d_in, const int* in_sizes, int n_in,
                              void* d_out, int out_size, void* d_ws, size_t ws_size,
                              hipStream_t stream) {
  const float* x      = (const float*)d_in[0];
  const float* wconv  = (const float*)d_in[1];
  const float* scale  = (const float*)d_in[2];
  const float* ln1w   = (const float*)d_in[3];
  const float* ln1b   = (const float*)d_in[4];
  const float* W1     = (const float*)d_in[5];
  const float* b1     = (const float*)d_in[6];
  const float* W2     = (const float*)d_in[7];
  const float* b2     = (const float*)d_in[8];
  const float* scalar = (const float*)d_in[9];
  const float* ln2w   = (const float*)d_in[10];
  const float* ln2b   = (const float*)d_in[11];
  float* out = (float*)d_out;

  char* ws = (char*)d_ws;
  unsigned short* xT   = (unsigned short*)ws; ws += (size_t)4 * 1024 * 2048 * 2;  // 16 MB
  unsigned short* T    = (unsigned short*)ws; ws += (size_t)2048 * 2048 * 2;      //  8 MB
  unsigned char* W1f8  = (unsigned char*)ws;  ws += (size_t)4096 * 1024;          //  4 MB
  unsigned char* W2f8  = (unsigned char*)ws;  ws += (size_t)4096 * 1024;          //  4 MB
  float* y             = (float*)ws;          ws += (size_t)8192 * 1024 * 4;      // 32 MB
  float* y1            = (float*)ws;          ws += (size_t)8192 * 1024 * 4;      // 32 MB
  unsigned short* x1b  = (unsigned short*)ws; ws += (size_t)8192 * 1024 * 2;      // 16 MB
  unsigned char* x1f8  = (unsigned char*)ws;  ws += (size_t)8192 * 1024;          //  8 MB
  unsigned char* h8    = (unsigned char*)ws;  ws += (size_t)8192 * 4096;          // 32 MB

  // prep
  cast_f8x64_kernel<<<4096, 256, 0, stream>>>(W1, (int*)W1f8);
  cast_f8x64_kernel<<<4096, 256, 0, stream>>>(W2, (int*)W2f8);
  build_T_kernel<<<16384, 256, 0, stream>>>(wconv, T);
  transpose_cast_kernel<<<dim3(32, 64, 4), dim3(32, 8), 0, stream>>>(x, xT);

  // GEMM1 (bf16): per batch, conv = T @ xT_b^T ; y = x + scale*conv
  gemm_bt<<<dim3(128, 1, 4), 256, 0, stream>>>(
      T, xT, 1024, 2048, 2048, 0L, (long)1024 * 2048, (long)2048 * 1024,
      8, x, scale, y);
  // LN1 -> x1 (bf16 residual + fp8 GEMM operand)
  ln_kernel<<<8192, 256, 0, stream>>>(y, ln1w, ln1b, x1b, (int*)x1f8);
  // GEMM2 (fp8): h = gelu(x1 @ W1^T + b1) -> fp8; 64x32 blocks, rect 16x16, 2 XCD cols
  gemm_f8<2><<<dim3(2048, 1, 1), 256, 0, stream>>>(
      x1f8, W1f8, 4096, 1024, 1024, 0L, 0L, 0L,
      16, 16, 2, b1, nullptr, h8);
  // GEMM3 (fp8) split-K=2: y/y1 = partial h @ W2^T; per z 64x8 blocks, rect 8x8
  gemm_f8<0><<<dim3(512, 1, 2), 256, 0, stream>>>(
      h8, W2f8, 1024, 4096, 2048, 2048L, 2048L, (long)8192 * 1024,
      8, 8, 1, nullptr, y, nullptr);
  // LN2 fused: out = LN(x1 + scalar*(y0+y1+b2))
  ln2_fused_kernel<<<8192, 256, 0, stream>>>(y, y1, x1b, b2, scalar, ln2w, ln2b, out);
}

// Round 5
// 286.740 us; speedup vs baseline: 1.4790x; 1.0889x over previous
//
#include <hip/hip_runtime.h>
#include <cstdint>

typedef float floatx4 __attribute__((ext_vector_type(4)));
typedef int intx8 __attribute__((ext_vector_type(8)));

__device__ __forceinline__ unsigned short f2b(float f) {
  union { float f; unsigned u; } v; v.f = f;
  return (unsigned short)((v.u + 0x7FFFu + ((v.u >> 16) & 1u)) >> 16);
}
__device__ __forceinline__ float b2f(unsigned short h) {
  union { unsigned u; float f; } v; v.u = ((unsigned)h) << 16;
  return v.f;
}

__device__ __forceinline__ void gload_lds16(const void* g, void* l) {
  __builtin_amdgcn_global_load_lds(
      (const __attribute__((address_space(1))) void*)g,
      (__attribute__((address_space(3))) void*)l, 16, 0, 0);
}

// ---------------- small prep kernels ----------------

// W (f32) -> fp8 e4m3 of (W * 64); consumed with MX block-scale 2^-6
__global__ void cast_f8x64_kernel(const float* __restrict__ in,
                                  int* __restrict__ out) {
  long i = (long)blockIdx.x * 256 + threadIdx.x;
  float4 v = ((const float4*)in)[i];
  int pk = __builtin_amdgcn_cvt_pk_fp8_f32(v.x * 64.0f, v.y * 64.0f, 0, false);
  pk = __builtin_amdgcn_cvt_pk_fp8_f32(v.z * 64.0f, v.w * 64.0f, pk, true);
  out[i] = pk;
}

// T8[n][m] = fp8(64 * w[n-m]) for m<=n else 0; 2048x2048 bytes, packed int writes
__global__ void build_T8_kernel(const float* __restrict__ w,
                                int* __restrict__ T8) {
  long i = (long)blockIdx.x * 256 + threadIdx.x;  // int index, 512 per row
  int n = (int)(i >> 9);
  int m0 = (int)(i & 511) * 4;
  float v[4];
#pragma unroll
  for (int r = 0; r < 4; ++r) {
    int m = m0 + r;
    v[r] = (m <= n) ? w[n - m] * 64.0f : 0.0f;
  }
  int pk = __builtin_amdgcn_cvt_pk_fp8_f32(v[0], v[1], 0, false);
  pk = __builtin_amdgcn_cvt_pk_fp8_f32(v[2], v[3], pk, true);
  T8[i] = pk;
}

// x (B,2048,1024) f32 -> xT8 (B,1024,2048) fp8 e4m3 (scale 2^0)
__global__ void transpose_cast_f8_kernel(const float* __restrict__ x,
                                         unsigned char* __restrict__ xT) {
  __shared__ float tile[32][33];
  int b = blockIdx.z;
  int n0 = blockIdx.y * 32;
  int d0 = blockIdx.x * 32;
  int tx = threadIdx.x;  // 0..31
  int ty = threadIdx.y;  // 0..7
  for (int i = ty; i < 32; i += 8)
    tile[i][tx] = x[((long)b * 2048 + n0 + i) * 1024 + d0 + tx];
  __syncthreads();
  float a = tile[ty * 4 + 0][tx];
  float c = tile[ty * 4 + 1][tx];
  float e = tile[ty * 4 + 2][tx];
  float f = tile[ty * 4 + 3][tx];
  int pk = __builtin_amdgcn_cvt_pk_fp8_f32(a, c, 0, false);
  pk = __builtin_amdgcn_cvt_pk_fp8_f32(e, f, pk, true);
  *(int*)(xT + ((long)b * 1024 + d0 + tx) * 2048 + n0 + ty * 4) = pk;
}

// ---------------- fp8 GEMM (MX-scaled): C = A @ B^T ----------------
// BM=BN=BK=128, mfma_scale_f32_16x16x128_f8f6f4, 4 waves of 64x64.
// LDS: 16 chunks (8 rows x 128B = 1024B) strided 1040B -> conflict-free b128
// fragment reads (row-start bank = 4*(row>>3), spans all 32 banks).
// EPI 0: Cb = bf16(acc)                     (split-K partial)
// EPI 1: Cf = resid + scale[row]*acc        (conv epilogue)
// EPI 2: C8 = fp8(gelu_pade(acc+bias))      (MLP up)
template <int EPI, int NT, bool TRI>
__global__ __launch_bounds__(256, 4) void gemm_f8(
    const unsigned char* __restrict__ A, const unsigned char* __restrict__ B,
    int Kstride, int Kloop, long zsA, long zsB, long zsC,
    int rx, int ryb, int gxn, unsigned sclA, unsigned sclB,
    const float* __restrict__ resid, const float* __restrict__ scale,
    const float* __restrict__ bias,
    float* __restrict__ Cf, unsigned short* __restrict__ Cb,
    unsigned char* __restrict__ C8) {
  __shared__ __align__(16) unsigned char As[16 * 1040];
  __shared__ __align__(16) unsigned char Bs[16 * 1040];
  const int tid = threadIdx.x;
  const int wid = tid >> 6;
  const int lane = tid & 63;
  const int quad = lane >> 4;
  const int l16 = lane & 15;
  const int wm = (wid >> 1) * 64;
  const int wn = (wid & 1) * 64;

  // XCD-rectangle block swizzle (xcd = bid&7 round-robin heuristic)
  const int bid = blockIdx.x;
  const int xcd = bid & 7;
  const int ib = bid >> 3;
  const int ci = ib % rx;
  const int ri = ib / rx;
  long bm, bn;
  if (TRI) {
    bm = (long)(ri == 0 ? xcd : 15 - xcd) * 128;
    bn = (long)ci * 128;
  } else {
    const int gx = xcd % gxn;
    const int gy = xcd / gxn;
    bm = (long)(gy * ryb + ri) * 128;
    bn = (long)(gx * rx + ci) * 128;
  }
  const int bz = blockIdx.z;
  const unsigned char* Ab = A + zsA * bz;
  const unsigned char* Bb = B + zsB * bz;

  floatx4 acc[4][4];
#pragma unroll
  for (int i = 0; i < 4; ++i)
#pragma unroll
    for (int j = 0; j < 4; ++j)
      acc[i][j] = floatx4{0.0f, 0.0f, 0.0f, 0.0f};

  // staging: 4 passes x 256 thr x 16B; chunk (p,w) -> LDS base (p*4+w)*1040
  const int srow = tid >> 3;          // 0..31 (row within pass)
  const int scol = (tid & 7) * 16;    // byte col
  const unsigned char* gA[4];
  const unsigned char* gB[4];
  unsigned char* lA[4];
  unsigned char* lB[4];
#pragma unroll
  for (int p = 0; p < 4; ++p) {
    gA[p] = Ab + (bm + p * 32 + srow) * (long)Kstride + scol;
    gB[p] = Bb + (bn + p * 32 + srow) * (long)Kstride + scol;
    lA[p] = As + (p * 4 + wid) * 1040;  // wave-uniform base (+lane*16 implicit)
    lB[p] = Bs + (p * 4 + wid) * 1040;
  }

  const int kend = TRI ? min(Kloop, (int)bm + 128) : Kloop;
  for (int kk = 0; kk < kend; kk += 128) {
    __syncthreads();
#pragma unroll
    for (int p = 0; p < 4; ++p) {
      gload_lds16(gA[p] + kk, lA[p]);
      gload_lds16(gB[p] + kk, lB[p]);
    }
    __syncthreads();
    intx8 af[4], bfr[4];
#pragma unroll
    for (int i = 0; i < 4; ++i) {
      const int ra = wm + i * 16 + l16;
      const int off = (ra >> 3) * 1040 + (ra & 7) * 128 + quad * 32;
      union { intx8 v; int4 q[2]; } u;
      u.q[0] = *(const int4*)(As + off);
      u.q[1] = *(const int4*)(As + off + 16);
      af[i] = u.v;
    }
#pragma unroll
    for (int j = 0; j < 4; ++j) {
      const int rb = wn + j * 16 + l16;
      const int off = (rb >> 3) * 1040 + (rb & 7) * 128 + quad * 32;
      union { intx8 v; int4 q[2]; } u;
      u.q[0] = *(const int4*)(Bs + off);
      u.q[1] = *(const int4*)(Bs + off + 16);
      bfr[j] = u.v;
    }
#pragma unroll
    for (int i = 0; i < 4; ++i)
#pragma unroll
      for (int j = 0; j < 4; ++j)
        acc[i][j] = __builtin_amdgcn_mfma_scale_f32_16x16x128_f8f6f4(
            af[i], bfr[j], acc[i][j], 0 /*fp8*/, 0 /*fp8*/,
            0, sclA, 0, sclB);
  }

#pragma unroll
  for (int i = 0; i < 4; ++i)
#pragma unroll
    for (int j = 0; j < 4; ++j)
#pragma unroll
      for (int r = 0; r < 4; ++r) {
        long row = bm + wm + i * 16 + quad * 4 + r;
        long col = bn + wn + j * 16 + l16;
        long idx = (long)bz * zsC + row * (long)NT + col;
        float v = acc[i][j][r];
        if (EPI == 0) {
          Cb[idx] = f2b(v);
        } else if (EPI == 1) {
          Cf[idx] = resid[idx] + scale[row] * v;
        } else {
          v += bias[col];
          // tanh-form gelu via [3/2] Pade tanh, saturated: no exp needed.
          float u = v * (0.7978845608f + 0.0356774081f * v * v);
          float u2 = u * u;
          float t = __fdividef(u * (15.0f + u2), 15.0f + 6.0f * u2);
          t = fminf(fmaxf(t, -1.0f), 1.0f);
          float g = 0.5f * v * (1.0f + t);
          int pk = __builtin_amdgcn_cvt_pk_fp8_f32(g, 0.0f, 0, false);
          C8[idx] = (unsigned char)(pk & 0xFF);
        }
      }
}

// ---------------- LayerNorm over D=1024, one block per row ----------------
// outputs bf16 (LN2 residual) + fp8 (GEMM2 A operand)
__global__ __launch_bounds__(256) void ln_kernel(
    const float* __restrict__ in, const float* __restrict__ w,
    const float* __restrict__ b, unsigned short* __restrict__ outb,
    int* __restrict__ outf8) {
  const long row = blockIdx.x;
  const int tid = threadIdx.x;
  float4 v = ((const float4*)in)[row * 256 + tid];
  float s = v.x + v.y + v.z + v.w;
  float ss = v.x * v.x + v.y * v.y + v.z * v.z + v.w * v.w;
#pragma unroll
  for (int off = 32; off > 0; off >>= 1) {
    s += __shfl_down(s, off);
    ss += __shfl_down(ss, off);
  }
  __shared__ float red[8];
  const int wid = tid >> 6, lane = tid & 63;
  if (lane == 0) { red[wid] = s; red[4 + wid] = ss; }
  __syncthreads();
  s = red[0] + red[1] + red[2] + red[3];
  ss = red[4] + red[5] + red[6] + red[7];
  const float mu = s * (1.0f / 1024.0f);
  const float var = ss * (1.0f / 1024.0f) - mu * mu;
  const float rs = rsqrtf(var + 1e-5f);
  float4 wv = ((const float4*)w)[tid];
  float4 bv = ((const float4*)b)[tid];
  float o0 = (v.x - mu) * rs * wv.x + bv.x;
  float o1 = (v.y - mu) * rs * wv.y + bv.y;
  float o2 = (v.z - mu) * rs * wv.z + bv.z;
  float o3 = (v.w - mu) * rs * wv.w + bv.w;
  ushort4 u{f2b(o0), f2b(o1), f2b(o2), f2b(o3)};
  ((ushort4*)outb)[row * 256 + tid] = u;
  int pk = __builtin_amdgcn_cvt_pk_fp8_f32(o0, o1, 0, false);
  pk = __builtin_amdgcn_cvt_pk_fp8_f32(o2, o3, pk, true);
  outf8[row * 256 + tid] = pk;
}

// LN2 fused: v = x1 + scalar*(y0+y1+b2); out = LN(v)*w + b  (y0/y1 bf16 partials)
__global__ __launch_bounds__(256) void ln2_fused_kernel(
    const unsigned short* __restrict__ y0, const unsigned short* __restrict__ y1,
    const unsigned short* __restrict__ x1b, const float* __restrict__ b2,
    const float* __restrict__ scalar_p, const float* __restrict__ w,
    const float* __restrict__ b, float* __restrict__ out) {
  const long row = blockIdx.x;
  const int tid = threadIdx.x;
  ushort4 a4 = ((const ushort4*)y0)[row * 256 + tid];
  ushort4 c4 = ((const ushort4*)y1)[row * 256 + tid];
  ushort4 xr = ((const ushort4*)x1b)[row * 256 + tid];
  float4 bias = ((const float4*)b2)[tid];
  const float scl = scalar_p[0];
  float4 v;
  v.x = b2f(xr.x) + scl * (b2f(a4.x) + b2f(c4.x) + bias.x);
  v.y = b2f(xr.y) + scl * (b2f(a4.y) + b2f(c4.y) + bias.y);
  v.z = b2f(xr.z) + scl * (b2f(a4.z) + b2f(c4.z) + bias.z);
  v.w = b2f(xr.w) + scl * (b2f(a4.w) + b2f(c4.w) + bias.w);
  float s = v.x + v.y + v.z + v.w;
  float ss = v.x * v.x + v.y * v.y + v.z * v.z + v.w * v.w;
#pragma unroll
  for (int off = 32; off > 0; off >>= 1) {
    s += __shfl_down(s, off);
    ss += __shfl_down(ss, off);
  }
  __shared__ float red[8];
  const int wid = tid >> 6, lane = tid & 63;
  if (lane == 0) { red[wid] = s; red[4 + wid] = ss; }
  __syncthreads();
  s = red[0] + red[1] + red[2] + red[3];
  ss = red[4] + red[5] + red[6] + red[7];
  const float mu = s * (1.0f / 1024.0f);
  const float var = ss * (1.0f / 1024.0f) - mu * mu;
  const float rs = rsqrtf(var + 1e-5f);
  float4 wv = ((const float4*)w)[tid];
  float4 bv = ((const float4*)b)[tid];
  float4 o;
  o.x = (v.x - mu) * rs * wv.x + bv.x;
  o.y = (v.y - mu) * rs * wv.y + bv.y;
  o.z = (v.z - mu) * rs * wv.z + bv.z;
  o.w = (v.w - mu) * rs * wv.w + bv.w;
  ((float4*)out)[row * 256 + tid] = o;
}

// ---------------- launch ----------------
extern "C" void kernel_launch(void* const* d_in, const int* in_sizes, int n_in,
                              void* d_out, int out_size, void* d_ws, size_t ws_size,
                              hipStream_t stream) {
  const float* x      = (const float*)d_in[0];
  const float* wconv  = (const float*)d_in[1];
  const float* scale  = (const float*)d_in[2];
  const float* ln1w   = (const float*)d_in[3];
  const float* ln1b   = (const float*)d_in[4];
  const float* W1     = (const float*)d_in[5];
  const float* b1     = (const float*)d_in[6];
  const float* W2     = (const float*)d_in[7];
  const float* b2     = (const float*)d_in[8];
  const float* scalar = (const float*)d_in[9];
  const float* ln2w   = (const float*)d_in[10];
  const float* ln2b   = (const float*)d_in[11];
  float* out = (float*)d_out;

  const unsigned SCL_1  = 0x7F7F7F7Fu;  // 2^0 per-block scales
  const unsigned SCL_64 = 0x79797979u;  // 2^-6 (operand pre-scaled x64)

  char* ws = (char*)d_ws;
  unsigned char* xT8   = (unsigned char*)ws;  ws += (size_t)4 * 1024 * 2048;     //  8 MB
  unsigned char* T8    = (unsigned char*)ws;  ws += (size_t)2048 * 2048;         //  4 MB
  unsigned char* W1f8  = (unsigned char*)ws;  ws += (size_t)4096 * 1024;         //  4 MB
  unsigned char* W2f8  = (unsigned char*)ws;  ws += (size_t)4096 * 1024;         //  4 MB
  float* y             = (float*)ws;          ws += (size_t)8192 * 1024 * 4;     // 32 MB
  unsigned short* yb   = (unsigned short*)ws; ws += (size_t)2 * 8192 * 1024 * 2; // 32 MB (split-K bf16 partials)
  unsigned short* x1b  = (unsigned short*)ws; ws += (size_t)8192 * 1024 * 2;     // 16 MB
  unsigned char* x1f8  = (unsigned char*)ws;  ws += (size_t)8192 * 1024;         //  8 MB
  unsigned char* h8    = (unsigned char*)ws;  ws += (size_t)8192 * 4096;         // 32 MB

  // prep
  cast_f8x64_kernel<<<4096, 256, 0, stream>>>(W1, (int*)W1f8);
  cast_f8x64_kernel<<<4096, 256, 0, stream>>>(W2, (int*)W2f8);
  build_T8_kernel<<<4096, 256, 0, stream>>>(wconv, (int*)T8);
  transpose_cast_f8_kernel<<<dim3(32, 64, 4), dim3(32, 8), 0, stream>>>(x, xT8);

  // GEMM1 (fp8, TRI): per batch, conv = T @ xT_b^T ; y = x + scale*conv
  gemm_f8<1, 1024, true><<<dim3(128, 1, 4), 256, 0, stream>>>(
      T8, xT8, 2048, 2048, 0L, (long)1024 * 2048, (long)2048 * 1024,
      8, 0, 0, SCL_64, SCL_1, x, scale, nullptr, y, nullptr, nullptr);
  // LN1 -> x1 (bf16 residual + fp8 GEMM operand)
  ln_kernel<<<8192, 256, 0, stream>>>(y, ln1w, ln1b, x1b, (int*)x1f8);
  // GEMM2 (fp8): h = gelu(x1 @ W1^T + b1) -> fp8; rect 16x16, XCD grid 2 wide
  gemm_f8<2, 4096, false><<<dim3(2048, 1, 1), 256, 0, stream>>>(
      x1f8, W1f8, 1024, 1024, 0L, 0L, 0L,
      16, 16, 2, SCL_1, SCL_64, nullptr, nullptr, b1, nullptr, nullptr, h8);
  // GEMM3 (fp8) split-K=2: yb = bf16 partial h @ W2^T; rect 8x8 per XCD
  gemm_f8<0, 1024, false><<<dim3(512, 1, 2), 256, 0, stream>>>(
      h8, W2f8, 4096, 2048, 2048L, 2048L, (long)8192 * 1024,
      8, 8, 1, SCL_1, SCL_64, nullptr, nullptr, nullptr, nullptr, yb, nullptr);
  // LN2 fused: out = LN(x1 + scalar*(yb0+yb1+b2))
  ln2_fused_kernel<<<8192, 256, 0, stream>>>(
      yb, yb + (size_t)8192 * 1024, x1b, b2, scalar, ln2w, ln2b, out);
}